// Round 1
// 161.158 us; speedup vs baseline: 1.0192x; 1.0192x over previous
//
#include <hip/hip_runtime.h>
#include <hip/hip_bf16.h>
#include <math.h>

#define NN 2048
#define BB 32
#define NT 64                 // total K-dim MFMA iterations: 2048 / 32
#define NBLK 256              // block = (osc_tile 0..127, batch_half 0..1)
#define DT_C 0.1f
#define PI_F 3.14159265358979323846f
#define TWO_PI_F 6.28318530717958647692f
#define MAGIC 0x5EED5EEDu

// ws layout (sync words line-padded):
//   EPOCH @ 0, READY @ 256, FLAG b @ 512 + 256*b (b<256)  -> ends at ~66 KB
//   ACC @ 80 KB: sin[32], cos[32] fp32 sums + arrival counter (atomic tail)
//   tables @ 128 KB: 10 per-step packed tables, reverse order, 1 MB apart
#define EPOCH_OFF  0
#define READY_OFF  256
#define FLAG_OFF   512
#define FLAG_STRIDE 256
#define ACC_OFF    81920
#define TAB_BASE   131072
#define TAB_STRIDE (1u << 20)

typedef __attribute__((ext_vector_type(8))) short short8;
typedef __attribute__((ext_vector_type(4))) float floatx4;

__device__ __forceinline__ unsigned short f2bf(float x) {
    union { float f; unsigned int u; } v; v.f = x;
    unsigned int r = v.u + 0x7FFFu + ((v.u >> 16) & 1u);
    return (unsigned short)(r >> 16);
}

// sc1 write-through store / L2-bypass load (agent-coherent, no cache walks)
__device__ __forceinline__ void st_sc(unsigned int* p, unsigned int v) {
    __hip_atomic_store(p, v, __ATOMIC_RELAXED, __HIP_MEMORY_SCOPE_AGENT);
}
__device__ __forceinline__ unsigned int ld_sc(const unsigned int* p) {
    return __hip_atomic_load((unsigned int*)p, __ATOMIC_RELAXED,
                             __HIP_MEMORY_SCOPE_AGENT);
}

// Round-11 aggregator barrier. Arrivals: one line-padded sc1 store per block.
// Block 0 wave 0 gathers 256 flags (4/lane) and publishes ONE epoch word.
// KEY FIX vs round 10: the 4 flag loads are issued UNCONDITIONALLY and
// combined bitwise -> 1 L3 round trip per poll iteration. The old
// short-circuit && serialized 4 dependent L3 RTs (~1.6 us/iter).
// __syncthreads drains vmcnt -> table sc1 stores are at L3 before the flag.
__device__ __forceinline__ void gridbar(char* wsb, unsigned int tgt) {
    __syncthreads();
    unsigned int* epoch = (unsigned int*)(wsb + EPOCH_OFF);
    if (blockIdx.x == 0) {
        if (threadIdx.x == 0)
            st_sc((unsigned int*)(wsb + FLAG_OFF), tgt);
        if (threadIdx.x < 64) {
            const int lane = threadIdx.x;
            const unsigned int* f0 = (const unsigned int*)(wsb + FLAG_OFF + (size_t)(4 * lane + 0) * FLAG_STRIDE);
            const unsigned int* f1 = (const unsigned int*)(wsb + FLAG_OFF + (size_t)(4 * lane + 1) * FLAG_STRIDE);
            const unsigned int* f2 = (const unsigned int*)(wsb + FLAG_OFF + (size_t)(4 * lane + 2) * FLAG_STRIDE);
            const unsigned int* f3 = (const unsigned int*)(wsb + FLAG_OFF + (size_t)(4 * lane + 3) * FLAG_STRIDE);
            for (;;) {
                unsigned int v0 = ld_sc(f0);   // 4 independent loads, all in
                unsigned int v1 = ld_sc(f1);   // flight before the compare:
                unsigned int v2 = ld_sc(f2);   // one RT, not four
                unsigned int v3 = ld_sc(f3);
                bool ok = (v0 >= tgt) & (v1 >= tgt) & (v2 >= tgt) & (v3 >= tgt);
                if (__all(ok)) break;
                __builtin_amdgcn_s_sleep(2);
            }
            if (lane == 0) st_sc(epoch, tgt);
        }
    } else {
        if (threadIdx.x == 0) {
            st_sc((unsigned int*)(wsb + FLAG_OFF + (size_t)blockIdx.x * FLAG_STRIDE), tgt);
            while (ld_sc(epoch) < tgt)
                __builtin_amdgcn_s_sleep(4);
        }
    }
    __syncthreads();
}

// unpack packed word pair {(s<<16)|c} x2 -> packed bf16x2 sin and cos
__device__ __forceinline__ void unpack2(unsigned int lo, unsigned int hi,
                                        unsigned int& sp, unsigned int& cp) {
    sp = __builtin_amdgcn_perm(hi, lo, 0x07060302u);  // {s1,s0}
    cp = __builtin_amdgcn_perm(hi, lo, 0x05040100u);  // {c1,c0}
}

// ROUND-11: sync-latency attack on the round-10 structure (compute loop
// unchanged). (a) parallel flag gather in gridbar (see above); (b) the final
// gridbar + TAB(10) store + coherence re-read pass are replaced by an atomic
// tail: each block's wave 0 shuffle-reduces its 16-osc partial sin/cos sums
// per batch row, one 32-lane global_atomic_add_f32 publishes them, a release
// counter increment detects the 256th arrival, which computes coh[32] from
// the fp32 sums (better precision than the old bf16-table path).
// Fragment layout (m89/m91-verified): A: lane holds A[m=lane&15][k=(lane>>4)*8+j];
// B mirrored; D: row(batch)=(lane>>4)*4+r, col(osc)=lane&15.
__global__ void __launch_bounds__(128, 1) kuramoto_fused(
    const float* __restrict__ theta0, const float* __restrict__ K,
    const float* __restrict__ omega, const float* __restrict__ K_global,
    const float* __restrict__ mu_gate,
    float* __restrict__ theta_out, float* __restrict__ coh,
    char* __restrict__ wsb)
{
    const int tid  = threadIdx.x;
    const int kh   = tid >> 6;              // K-half this wave covers: 0 or 1
    const int lane = tid & 63;
    const int lrow = lane & 15;
    const int kq   = lane >> 4;             // 0..3
    const int tile = blockIdx.x >> 1;
    const int bh   = blockIdx.x & 1;        // batch half
    const int i0   = tile * 16;
    const int b0   = bh * 16;
    const int i    = i0 + lrow;

    // one-time: drop pre-kernel (poison) lines from local caches before any
    // cached table read (belt-and-braces alongside launch acquire)
    __builtin_amdgcn_fence(__ATOMIC_ACQUIRE, "agent");

    // block 0 zeroes the (poisoned) sync words + atomic-tail accumulators
    // before the ready handshake
    if (blockIdx.x == 0) {
        if (tid < 128) {
            st_sc((unsigned int*)(wsb + FLAG_OFF + (size_t)(2 * tid) * FLAG_STRIDE), 0u);
            st_sc((unsigned int*)(wsb + FLAG_OFF + (size_t)(2 * tid + 1) * FLAG_STRIDE), 0u);
        }
        if (tid < 66)                       // sin[32] cos[32] cnt (+pad)
            st_sc((unsigned int*)(wsb + ACC_OFF) + tid, 0u);
        if (tid == 0)
            st_sc((unsigned int*)(wsb + EPOCH_OFF), 0u);
    }

    // ---- K rows i0..i0+15 -> LDS as pre-scaled bf16 B-fragments ----
    // Batched loads: 16 float4 in flight per thread before converting.
    __shared__ short8 kb[NT * 64];          // 64 KB, kb[t*64 + lane]
    __shared__ floatx4 red[2][64];          // K-split partial P/Q exchange
    const float kscale = mu_gate[0] * 0.5f; // MU_BRANCH_SCALE fold
    for (int g = 0; g < 4; ++g) {
        const int tb = kh * 32 + g * 8;
        float4 buf[16];
        #pragma unroll
        for (int j = 0; j < 8; ++j) {
            const float4* kp = (const float4*)(K + (size_t)i * NN + (tb + j) * 32 + kq * 8);
            buf[2 * j]     = kp[0];
            buf[2 * j + 1] = kp[1];
        }
        #pragma unroll
        for (int j = 0; j < 8; ++j) {
            float4 x = buf[2 * j], y = buf[2 * j + 1];
            short8 f;
            f[0] = (short)f2bf(x.x * kscale); f[1] = (short)f2bf(x.y * kscale);
            f[2] = (short)f2bf(x.z * kscale); f[3] = (short)f2bf(x.w * kscale);
            f[4] = (short)f2bf(y.x * kscale); f[5] = (short)f2bf(y.y * kscale);
            f[6] = (short)f2bf(y.z * kscale); f[7] = (short)f2bf(y.w * kscale);
            kb[(tb + j) * 64 + lane] = f;
        }
    }

    // per-step table s lives at wsb + TAB_BASE + (10-s)*TAB_STRIDE
    #define TAB(s) ((unsigned int*)(wsb + TAB_BASE + (size_t)(10 - (s)) * TAB_STRIDE))

    const float coef = K_global[0] * (DT_C / (float)NN);    // DT folded in

    // wave 0 owns theta for this block's 16x16 tile
    float th[4], sb[4], cbv[4], om_dt = 0.f;
    if (kh == 0) {
        om_dt = omega[i] * DT_C;
        #pragma unroll
        for (int r = 0; r < 4; ++r) {
            size_t off = (size_t)(b0 + kq * 4 + r) * NN + i;
            th[r] = theta0[off];
            __sincosf(th[r], &sb[r], &cbv[r]);
            st_sc(&TAB(0)[off], ((unsigned int)f2bf(sb[r]) << 16) | f2bf(cbv[r]));
        }
    }

    // drain zeros (block 0) + TAB(0) stores + kb staging; then ready handshake
    __syncthreads();
    if (tid == 0) {
        unsigned int* ready = (unsigned int*)(wsb + READY_OFF);
        if (blockIdx.x == 0) {
            st_sc(ready, MAGIC);            // zeros at L3 (vmcnt drained)
        } else {
            while (ld_sc(ready) != MAGIC)   // => zeros visible before our flag
                __builtin_amdgcn_s_sleep(8);
        }
    }
    gridbar(wsb, 1u);                       // table 0 complete everywhere

    const int c0 = (blockIdx.x * 5) & 15;   // per-block K-loop rotation

    for (int step = 0; step < 10; ++step) {
        const uint4* U = (const uint4*)(TAB(step) + (size_t)(b0 + lrow) * NN);
        unsigned int* tabn = TAB(step + 1);

        floatx4 p0 = {0.f,0.f,0.f,0.f}, p1 = {0.f,0.f,0.f,0.f};
        floatx4 q0 = {0.f,0.f,0.f,0.f}, q1 = {0.f,0.f,0.f,0.f};
        #pragma unroll 4
        for (int c = 0; c < 16; ++c) {      // this wave's K-half: 16 x 2 chunks
            const int t  = kh * 32 + 2 * ((c + c0) & 15);
            const int a0 = 8 * t + 2 * kq;  // uint4 idx: words j0..j0+7
            uint4 ua = U[a0];
            uint4 ub = U[a0 + 1];
            uint4 va = U[a0 + 8];           // chunk t+1
            uint4 vb = U[a0 + 9];
            union { short8 v; unsigned int u[4]; } as0, ac0, as1, ac1;
            unpack2(ua.x, ua.y, as0.u[0], ac0.u[0]);
            unpack2(ua.z, ua.w, as0.u[1], ac0.u[1]);
            unpack2(ub.x, ub.y, as0.u[2], ac0.u[2]);
            unpack2(ub.z, ub.w, as0.u[3], ac0.u[3]);
            unpack2(va.x, va.y, as1.u[0], ac1.u[0]);
            unpack2(va.z, va.w, as1.u[1], ac1.u[1]);
            unpack2(vb.x, vb.y, as1.u[2], ac1.u[2]);
            unpack2(vb.z, vb.w, as1.u[3], ac1.u[3]);
            short8 bk0 = kb[t * 64 + lane];
            short8 bk1 = kb[(t + 1) * 64 + lane];
            p0 = __builtin_amdgcn_mfma_f32_16x16x32_bf16(as0.v, bk0, p0, 0, 0, 0);
            q0 = __builtin_amdgcn_mfma_f32_16x16x32_bf16(ac0.v, bk0, q0, 0, 0, 0);
            p1 = __builtin_amdgcn_mfma_f32_16x16x32_bf16(as1.v, bk1, p1, 0, 0, 0);
            q1 = __builtin_amdgcn_mfma_f32_16x16x32_bf16(ac1.v, bk1, q1, 0, 0, 0);
        }
        floatx4 P = p0 + p1;
        floatx4 Q = q0 + q1;

        // K-split reduction: wave 1 publishes partials, wave 0 combines
        if (kh == 1) { red[0][lane] = P; red[1][lane] = Q; }
        __syncthreads();
        if (kh == 0) {
            P += red[0][lane];
            Q += red[1][lane];
            #pragma unroll
            for (int r = 0; r < 4; ++r) {
                float coup = cbv[r] * P[r] - sb[r] * Q[r];
                float tn = th[r] + om_dt + coef * coup;
                if (tn > PI_F)        tn -= TWO_PI_F;   // wrap to (-pi, pi]
                else if (tn <= -PI_F) tn += TWO_PI_F;
                th[r] = tn;
                __sincosf(tn, &sb[r], &cbv[r]);
                size_t off = (size_t)(b0 + kq * 4 + r) * NN + i;
                if (step < 9) {
                    st_sc(&tabn[off], ((unsigned int)f2bf(sb[r]) << 16) | f2bf(cbv[r]));
                } else {
                    theta_out[off] = tn;    // visible at kernel end
                }
            }
        }
        if (step < 9) gridbar(wsb, (unsigned)(step + 2));
    }

    // ---- atomic coherence tail (replaces final gridbar + TAB(10) pass) ----
    // wave 0 holds fp32 sin/cos of the final theta for rows b0+4*kq+r,
    // osc column i0+lrow. Reduce over the 16 osc lanes of each kq group,
    // publish via one 32-lane device-scope f32 atomic, count arrivals.
    if (kh == 0) {
        #pragma unroll
        for (int m = 1; m < 16; m <<= 1) {
            #pragma unroll
            for (int r = 0; r < 4; ++r) {
                sb[r]  += __shfl_xor(sb[r],  m, 64);
                cbv[r] += __shfl_xor(cbv[r], m, 64);
            }
        }
        float* sacc = (float*)(wsb + ACC_OFF);
        float* cacc = sacc + 32;
        const int j = lane & 15;
        if (j < 8) {                        // 32 lanes, 32 distinct addresses
            const int r   = j & 3;
            const int row = b0 + 4 * kq + r;
            float  val = (j < 4) ? sb[r] : cbv[r];
            float* dst = (j < 4) ? (sacc + row) : (cacc + row);
            __hip_atomic_fetch_add(dst, val, __ATOMIC_RELAXED,
                                   __HIP_MEMORY_SCOPE_AGENT);
        }
        // wave-level drain so all lanes' sum-atomics complete before arrival
        __builtin_amdgcn_s_waitcnt(0);
        unsigned int old = 0u;
        if (lane == 0) {
            unsigned int* cnt = (unsigned int*)(sacc + 64);
            old = __hip_atomic_fetch_add(cnt, 1u, __ATOMIC_ACQ_REL,
                                         __HIP_MEMORY_SCOPE_AGENT);
        }
        const int islast = __shfl((int)(old == NBLK - 1), 0, 64);
        if (islast) {                       // 256th arrival: all sums at L3
            __builtin_amdgcn_fence(__ATOMIC_ACQUIRE, "agent");
            if (lane < BB) {
                float s = __hip_atomic_load(sacc + lane, __ATOMIC_RELAXED,
                                            __HIP_MEMORY_SCOPE_AGENT);
                float c = __hip_atomic_load(cacc + lane, __ATOMIC_RELAXED,
                                            __HIP_MEMORY_SCOPE_AGENT);
                float sm = s * (1.0f / NN), cm = c * (1.0f / NN);
                coh[lane] = sqrtf(sm * sm + cm * cm);
            }
        }
    }
    #undef TAB
}

extern "C" void kernel_launch(void* const* d_in, const int* in_sizes, int n_in,
                              void* d_out, int out_size, void* d_ws, size_t ws_size,
                              hipStream_t stream)
{
    const float* theta0   = (const float*)d_in[0];   // 32*2048
    const float* K        = (const float*)d_in[1];   // 2048*2048
    const float* omega    = (const float*)d_in[2];   // 2048
    const float* K_global = (const float*)d_in[3];   // 1
    const float* mu_gate  = (const float*)d_in[4];   // 1

    float* theta_out = (float*)d_out;                // 65536 floats
    float* coh       = theta_out + BB * NN;          // 32 floats

    // ws needs ~10.6 MB: 128 KB sync region + 10 tables (reverse, 1 MB apart)
    kuramoto_fused<<<dim3(NBLK), dim3(128), 0, stream>>>(
        theta0, K, omega, K_global, mu_gate, theta_out, coh, (char*)d_ws);
}